// Round 1
// baseline (321.026 us; speedup 1.0000x reference)
//
#include <hip/hip_runtime.h>

#define CH   288      // channels = GROUPS * K*K
#define GRPS 32
#define CPG  9        // channels per group == K*K
#define IMH  64
#define IMW  64
#define HW   4096
#define NB   8
#define BN_EPS 1e-5f

// ---------------------------------------------------------------------------
// K1: tmp[b,m,p] = relu( sum_k Wi[m,k] * x[b,k,p] + bi[m] )
// Tiles: BM=32, BN=128, BK=16; 256 threads; 4x4 micro-tile.
// tmp is written into d_out (in-place staging buffer).
// ---------------------------------------------------------------------------
__global__ __launch_bounds__(256) void k_gemm1(const float* __restrict__ x,
                                               const float* __restrict__ Wi,
                                               const float* __restrict__ bi,
                                               float* __restrict__ tmp) {
    __shared__ float Ast[16][36];   // A tile, transposed [k][m], padded
    __shared__ float Bs[16][128];   // B tile [k][n]

    const int tid = threadIdx.x;
    const int tn  = tid & 31;   // n quad index
    const int tm  = tid >> 5;   // m quad index (0..7)
    const int n0  = blockIdx.x * 128;
    const int m0  = blockIdx.y * 32;
    const int bb  = blockIdx.z;
    const float* xb = x + (size_t)bb * CH * HW;

    const int a_m = tid >> 3;         // 0..31
    const int a_k = (tid & 7) * 2;    // 0,2,...,14
    const int b_row = tid >> 5;       // 0..7
    const int b_col = (tid & 31) * 4;

    float acc[4][4] = {};

    for (int k0 = 0; k0 < CH; k0 += 16) {
        // stage A (32x16, transposed)
        const float2 av = *(const float2*)(Wi + (size_t)(m0 + a_m) * CH + k0 + a_k);
        Ast[a_k][a_m]     = av.x;
        Ast[a_k + 1][a_m] = av.y;
        // stage B (16x128)
        const float4 bv0 = *(const float4*)(xb + (size_t)(k0 + b_row) * HW + n0 + b_col);
        const float4 bv1 = *(const float4*)(xb + (size_t)(k0 + b_row + 8) * HW + n0 + b_col);
        *(float4*)&Bs[b_row][b_col]     = bv0;
        *(float4*)&Bs[b_row + 8][b_col] = bv1;
        __syncthreads();
        #pragma unroll
        for (int kk = 0; kk < 16; ++kk) {
            const float4 a4 = *(const float4*)&Ast[kk][tm * 4];
            const float4 b4 = *(const float4*)&Bs[kk][tn * 4];
            acc[0][0] += a4.x * b4.x; acc[0][1] += a4.x * b4.y;
            acc[0][2] += a4.x * b4.z; acc[0][3] += a4.x * b4.w;
            acc[1][0] += a4.y * b4.x; acc[1][1] += a4.y * b4.y;
            acc[1][2] += a4.y * b4.z; acc[1][3] += a4.y * b4.w;
            acc[2][0] += a4.z * b4.x; acc[2][1] += a4.z * b4.y;
            acc[2][2] += a4.z * b4.z; acc[2][3] += a4.z * b4.w;
            acc[3][0] += a4.w * b4.x; acc[3][1] += a4.w * b4.y;
            acc[3][2] += a4.w * b4.z; acc[3][3] += a4.w * b4.w;
        }
        __syncthreads();
    }

    #pragma unroll
    for (int im = 0; im < 4; ++im) {
        const int m = m0 + tm * 4 + im;
        const float bias = bi[m];
        float4 o;
        o.x = fmaxf(acc[im][0] + bias, 0.0f);
        o.y = fmaxf(acc[im][1] + bias, 0.0f);
        o.z = fmaxf(acc[im][2] + bias, 0.0f);
        o.w = fmaxf(acc[im][3] + bias, 0.0f);
        *(float4*)(tmp + ((size_t)bb * CH + m) * HW + n0 + tn * 4) = o;
    }
}

// ---------------------------------------------------------------------------
// K2: per-channel BN stats over (N,H,W); emits folded scale/shift.
// scale[c] = gamma[c]*rsqrt(var+eps); shift[c] = beta[c] - mean[c]*scale[c]
// ---------------------------------------------------------------------------
__global__ __launch_bounds__(256) void k_stats(const float* __restrict__ tmp,
                                               const float* __restrict__ gamma,
                                               const float* __restrict__ beta,
                                               float* __restrict__ scale,
                                               float* __restrict__ shift) {
    const int c = blockIdx.x;
    const int tid = threadIdx.x;
    float s1 = 0.0f, s2 = 0.0f;
    for (int b = 0; b < NB; ++b) {
        const float4* p = (const float4*)(tmp + ((size_t)b * CH + c) * HW);
        for (int i = tid; i < HW / 4; i += 256) {
            const float4 v = p[i];
            s1 += v.x + v.y + v.z + v.w;
            s2 += v.x * v.x + v.y * v.y + v.z * v.z + v.w * v.w;
        }
    }
    __shared__ float r1[256], r2[256];
    r1[tid] = s1; r2[tid] = s2;
    __syncthreads();
    for (int s = 128; s > 0; s >>= 1) {
        if (tid < s) { r1[tid] += r1[tid + s]; r2[tid] += r2[tid + s]; }
        __syncthreads();
    }
    if (tid == 0) {
        const float inv = 1.0f / (float)(NB * HW);
        const float mean = r1[0] * inv;
        const float var  = r2[0] * inv - mean * mean;
        const float rs   = rsqrtf(var + BN_EPS);
        const float sc   = gamma[c] * rs;
        scale[c] = sc;
        shift[c] = beta[c] - mean * sc;
    }
}

// ---------------------------------------------------------------------------
// K2b: bo2[c] = bo[c] + sum_k Wo[c,k] * shift[k]   (one wave per channel)
// ---------------------------------------------------------------------------
__global__ __launch_bounds__(64) void k_foldbias(const float* __restrict__ Wo,
                                                 const float* __restrict__ bo,
                                                 const float* __restrict__ shift,
                                                 float* __restrict__ bo2) {
    const int c = blockIdx.x;
    const int t = threadIdx.x;
    float s = 0.0f;
    for (int k = t; k < CH; k += 64) s += Wo[(size_t)c * CH + k] * shift[k];
    #pragma unroll
    for (int off = 32; off > 0; off >>= 1) s += __shfl_down(s, off);
    if (t == 0) bo2[c] = bo[c] + s;
}

// ---------------------------------------------------------------------------
// K3: fused GEMM2 + involution, in-place over d_out.
// Block = full 288-channel column x 32-pixel tile (half image row).
//   ker[m,t] = sum_k Wo[m,k]*scale[k]*tmp[k,t] + bo2[m]   (kept in LDS)
//   out[ch,t] = sum_k ker[(ch/9)*9+k, t] * x[ch, h+di, w+dj]
// Column-local: block reads tmp only at its own pixels, then overwrites them.
// ---------------------------------------------------------------------------
#define PT 32
__global__ __launch_bounds__(256) void k_gemm2_invol(const float* __restrict__ x,
                                                     const float* __restrict__ Wo,
                                                     const float* __restrict__ scale,
                                                     const float* __restrict__ bo2,
                                                     float* __restrict__ io) {
    // Ast: [32][289] scaled transposed Wo tile; Ts: [32][32] tmp tile.
    // kerL: [288][33] aliases Ast region after the GEMM (9504 <= 10272 floats).
    __shared__ float smem[32 * 289 + 32 * 32];
    float* Ast  = smem;
    float* Ts   = smem + 32 * 289;
    float* kerL = smem;

    const int tid = threadIdx.x;
    const int tn  = tid & 7;    // pixel quad (t = tn*4 + j)
    const int tm  = tid >> 3;   // 0..31 ; m = tm + 32*i
    const int bb  = blockIdx.y;
    const int p0  = blockIdx.x * PT;
    const int h   = p0 >> 6;
    const int w0  = p0 & 63;
    const float* tmpb = io + (size_t)bb * CH * HW;

    const int am  = tid >> 3;         // A-load: m = am + 32*r
    const int ak4 = (tid & 7) * 4;    // A-load: k offset within tile

    float acc[9][4] = {};

    for (int k0 = 0; k0 < CH; k0 += 32) {
        const float4 sc4 = *(const float4*)(scale + k0 + ak4);
        #pragma unroll
        for (int r = 0; r < 9; ++r) {
            const int m = am + 32 * r;
            const float4 wv = *(const float4*)(Wo + (size_t)m * CH + k0 + ak4);
            Ast[(ak4 + 0) * 289 + m] = wv.x * sc4.x;
            Ast[(ak4 + 1) * 289 + m] = wv.y * sc4.y;
            Ast[(ak4 + 2) * 289 + m] = wv.z * sc4.z;
            Ast[(ak4 + 3) * 289 + m] = wv.w * sc4.w;
        }
        const float4 tv = *(const float4*)(tmpb + (size_t)(k0 + tm) * HW + p0 + tn * 4);
        *(float4*)&Ts[tm * 32 + tn * 4] = tv;
        __syncthreads();
        #pragma unroll 8
        for (int kk = 0; kk < 32; ++kk) {
            float a[9];
            #pragma unroll
            for (int i = 0; i < 9; ++i) a[i] = Ast[kk * 289 + tm + 32 * i];
            const float4 b4 = *(const float4*)&Ts[kk * 32 + tn * 4];
            #pragma unroll
            for (int i = 0; i < 9; ++i) {
                acc[i][0] += a[i] * b4.x;
                acc[i][1] += a[i] * b4.y;
                acc[i][2] += a[i] * b4.z;
                acc[i][3] += a[i] * b4.w;
            }
        }
        __syncthreads();   // last iteration: guards kerL aliasing below
    }

    // stage ker (+ bias) into LDS
    #pragma unroll
    for (int i = 0; i < 9; ++i) {
        const int m = tm + 32 * i;
        const float bv = bo2[m];
        #pragma unroll
        for (int j = 0; j < 4; ++j)
            kerL[m * 33 + tn * 4 + j] = acc[i][j] + bv;
    }
    __syncthreads();

    // involution + in-place output write (overwrites tmp at this pixel tile)
    const float* xb = x + (size_t)bb * CH * HW;
    #pragma unroll 1
    for (int i = 0; i < 9; ++i) {
        const int ch = tm + 32 * i;
        const int g  = ch / CPG;
        const int cb = g * CPG;
        float o[4] = {0.0f, 0.0f, 0.0f, 0.0f};
        #pragma unroll
        for (int k = 0; k < 9; ++k) {
            const int di = k / 3 - 1;
            const int dj = k % 3 - 1;
            const int hh = h + di;
            if (hh >= 0 && hh < IMH) {
                const float* kr = &kerL[(cb + k) * 33 + tn * 4];
                const float* xr = xb + (size_t)ch * HW + hh * IMW;
                #pragma unroll
                for (int j = 0; j < 4; ++j) {
                    const int ww = w0 + tn * 4 + j + dj;
                    const float xv = (ww >= 0 && ww < IMW) ? xr[ww] : 0.0f;
                    o[j] += kr[j] * xv;
                }
            }
        }
        float4 ov = {o[0], o[1], o[2], o[3]};
        *(float4*)(io + ((size_t)bb * CH + ch) * HW + p0 + tn * 4) = ov;
    }
}

// ---------------------------------------------------------------------------
extern "C" void kernel_launch(void* const* d_in, const int* in_sizes, int n_in,
                              void* d_out, int out_size, void* d_ws, size_t ws_size,
                              hipStream_t stream) {
    const float* x     = (const float*)d_in[0];
    const float* Wi    = (const float*)d_in[1];
    const float* bi    = (const float*)d_in[2];
    const float* gamma = (const float*)d_in[3];
    const float* beta  = (const float*)d_in[4];
    const float* Wo    = (const float*)d_in[5];
    const float* bo    = (const float*)d_in[6];
    float* out = (float*)d_out;

    float* scale = (float*)d_ws;        // [288]
    float* shift = scale + CH;          // [288]
    float* bo2   = shift + CH;          // [288]

    // tmp = relu(Wi@x + bi), staged in d_out
    k_gemm1<<<dim3(HW / 128, CH / 32, NB), 256, 0, stream>>>(x, Wi, bi, out);
    // BN stats -> folded scale/shift
    k_stats<<<dim3(CH), 256, 0, stream>>>(out, gamma, beta, scale, shift);
    // folded output bias
    k_foldbias<<<dim3(CH), 64, 0, stream>>>(Wo, bo, shift, bo2);
    // ker = (Wo*scale)@tmp + bo2 ; involution ; in-place overwrite of d_out
    k_gemm2_invol<<<dim3(HW / PT, NB), 256, 0, stream>>>(x, Wo, scale, bo2, out);
}